// Round 7
// baseline (888.883 us; speedup 1.0000x reference)
//
#include <hip/hip_runtime.h>

#define T_ 16
#define N_ 128
#define F_ 128

__device__ __forceinline__ float fast_tanh(float x) {
    // tanh(x) = 1 - 2/(exp(2x)+1); v_exp_f32 + native rcp-div. Handles +-inf correctly.
    float e = __expf(2.0f * x);
    return 1.0f - __fdividef(2.0f, e + 1.0f);
}

__device__ __forceinline__ float lrelu(float v) {
    return v >= 0.0f ? v : 0.01f * v;
}

// ---------------- D1: sim_cal(x0) + (role-split) W transpose + bnP/cnt zero ----------------
// grid (16, 17) x 256. by<16: sim blocks (t=bx, ch=by). by==16: prep blocks (16 x 256 = 4096 thr).
__global__ __launch_bounds__(256) void sim0_prep_k(const float* __restrict__ x,
                                                   const float* __restrict__ W,
                                                   float* __restrict__ WT,
                                                   float* __restrict__ bnP,
                                                   unsigned int* __restrict__ cnt,
                                                   float* __restrict__ out) {
    __shared__ float Xs[128][132];
    __shared__ float nrm[128];
    int tid = threadIdx.x;

    if (blockIdx.y == 16) {
        int idx4 = blockIdx.x * 256 + tid;       // 0..4095
        #pragma unroll
        for (int k = 0; k < 8; ++k) {
            int lin = k * 4096 + idx4;           // 0..32767
            int l = lin >> 14, idx = lin & 16383;
            int g = idx >> 7, f = idx & 127;
            WT[l * 16384 + f * 128 + g] = W[lin];
        }
        #pragma unroll
        for (int k = 0; k < 4; ++k) bnP[idx4 * 4 + k] = 0.0f;   // 16384 floats (2 layers x 32 buckets x 256)
        cnt[idx4] = 0u;                                          // 2 layers x 2048 counters
        return;
    }

    int t = blockIdx.x, ch = blockIdx.y;
    int m = tid & 127, rh = tid >> 7;
    const float* xt = x + (size_t)t * (N_ * F_);
    int fg = (tid & 31) * 4, ko = tid >> 5;

    for (int kb = 0; kb < 128; kb += 8) {
        int k = kb + ko;
        *(float4*)&Xs[k][fg] = *(const float4*)(xt + k * 128 + fg);
    }
    __syncthreads();

    if (tid < 128) {
        float s = 0.0f;
        #pragma unroll 8
        for (int f = 0; f < 128; f += 4) {
            float4 v = *(float4*)&Xs[m][f];
            s += v.x * v.x + v.y * v.y + v.z * v.z + v.w * v.w;
        }
        nrm[m] = sqrtf(s);
    }
    __syncthreads();

    float acc[4];
    #pragma unroll
    for (int r = 0; r < 4; ++r) acc[r] = 0.0f;

    for (int fc = 0; fc < 128; fc += 32) {
        float xm[32];
        #pragma unroll
        for (int f = 0; f < 32; f += 4) {
            float4 v = *(float4*)&Xs[m][fc + f];
            xm[f] = v.x; xm[f + 1] = v.y; xm[f + 2] = v.z; xm[f + 3] = v.w;
        }
        #pragma unroll
        for (int r = 0; r < 4; ++r) {
            int n = ch * 8 + rh * 4 + r;
            #pragma unroll
            for (int f = 0; f < 32; f += 4) {
                float4 v = *(float4*)&Xs[n][fc + f];
                acc[r] = fmaf(xm[f], v.x,
                         fmaf(xm[f + 1], v.y,
                         fmaf(xm[f + 2], v.z,
                         fmaf(xm[f + 3], v.w, acc[r]))));
            }
        }
    }

    float nm = nrm[m];
    size_t ob = (size_t)t * 2 * 16384;
    #pragma unroll
    for (int r = 0; r < 4; ++r) {
        int n = ch * 8 + rh * 4 + r;
        float denom = nrm[n] * nm + 1e-6f;
        float sim = __fdividef(acc[r], denom);
        out[ob + (size_t)n * 128 + m] = fminf(fmaxf(sim, 0.0f), 1.0f);
        out[ob + 16384 + (size_t)n * 128 + m] = fminf(fmaxf(1.0f - sim, 0.0f), 1.0f);
    }
}

// ---------------- D2/D4: edge update + partial aggregate + LAST-BLOCK node finisher ----------------
// grid 8192 (= (t*128+i)*4 + quarter), block 256 (jl 0..7, fg 0..31).
// Edge phase identical to proven R5 kernel. Quarter partials published with agent-scope
// atomic stores; per-row counter ACQ_REL; the 4th block computes h row, y row (GEMV vs WT),
// writes yb + bucketed BN partial sums (32 buckets -> 64 adds/address).
template<int LAYER>
__global__ __launch_bounds__(256) void edge_nk(const float* __restrict__ x0,
                                               const float* __restrict__ x1,
                                               const float* __restrict__ E,
                                               const float* __restrict__ ew,
                                               const float* __restrict__ eb,
                                               const float* __restrict__ cw,
                                               const float* __restrict__ WT,
                                               float* __restrict__ aggrP,
                                               unsigned int* __restrict__ cnt,
                                               float* __restrict__ yb,
                                               float* __restrict__ bnP) {
    __shared__ float4 red[256];
    __shared__ float hs[128];
    __shared__ float ya[128];
    __shared__ unsigned int sOld;
    int b = blockIdx.x;
    int ti = b >> 2, q = b & 3;          // ti = t*128+i, q = j-quarter
    int t = ti >> 7, i = ti & 127;
    int tid = threadIdx.x, jl = tid >> 5, fg = tid & 31;

    const float4* xt0 = (const float4*)(x0 + (size_t)t * 16384);
    const float4* xt1 = (const float4*)(x1 + (size_t)t * 16384);
    const float4* Ei  = (const float4*)(E + (size_t)ti * 16384);

    float w02 = ew[2], b0 = eb[0];
    float c0 = ew[0] + ew[1], nw01 = -ew[1];
    float c1 = 0.f, nw11 = 0.f, w12 = 0.f, b1 = 0.f;
    if constexpr (LAYER == 1) { c1 = ew[3] + ew[4]; nw11 = -ew[4]; w12 = ew[5]; b1 = eb[1]; }

    float4 xi0 = xt0[i * 32 + fg];
    float4 xi1 = xi0;
    if constexpr (LAYER == 1) xi1 = xt1[i * 32 + fg];

    float4 a = make_float4(0.f, 0.f, 0.f, 0.f);
    int jbase = q * 32;

    float4 xj0[4], ev[4], xj1[4];
    #pragma unroll
    for (int k = 0; k < 4; ++k) {
        int j = jbase + k * 8 + jl;
        ev[k]  = Ei[j * 32 + fg];
        xj0[k] = xt0[j * 32 + fg];
        if constexpr (LAYER == 1) xj1[k] = xt1[j * 32 + fg];
    }

    #pragma unroll
    for (int k = 0; k < 4; ++k) {
        int j = jbase + k * 8 + jl;
        float msk = (j != i) ? 1.0f : 0.0f;
        if constexpr (LAYER == 0) {
            a.x += msk * fast_tanh(fmaf(c0, xi0.x, fmaf(w02, ev[k].x, fmaf(nw01, xj0[k].x, b0))));
            a.y += msk * fast_tanh(fmaf(c0, xi0.y, fmaf(w02, ev[k].y, fmaf(nw01, xj0[k].y, b0))));
            a.z += msk * fast_tanh(fmaf(c0, xi0.z, fmaf(w02, ev[k].z, fmaf(nw01, xj0[k].z, b0))));
            a.w += msk * fast_tanh(fmaf(c0, xi0.w, fmaf(w02, ev[k].w, fmaf(nw01, xj0[k].w, b0))));
        } else {
            float e0x = fast_tanh(fmaf(c0, xi0.x, fmaf(w02, ev[k].x, fmaf(nw01, xj0[k].x, b0))));
            float e0y = fast_tanh(fmaf(c0, xi0.y, fmaf(w02, ev[k].y, fmaf(nw01, xj0[k].y, b0))));
            float e0z = fast_tanh(fmaf(c0, xi0.z, fmaf(w02, ev[k].z, fmaf(nw01, xj0[k].z, b0))));
            float e0w = fast_tanh(fmaf(c0, xi0.w, fmaf(w02, ev[k].w, fmaf(nw01, xj0[k].w, b0))));
            a.x += msk * fast_tanh(fmaf(c1, xi1.x, fmaf(w12, e0x, fmaf(nw11, xj1[k].x, b1))));
            a.y += msk * fast_tanh(fmaf(c1, xi1.y, fmaf(w12, e0y, fmaf(nw11, xj1[k].y, b1))));
            a.z += msk * fast_tanh(fmaf(c1, xi1.z, fmaf(w12, e0z, fmaf(nw11, xj1[k].z, b1))));
            a.w += msk * fast_tanh(fmaf(c1, xi1.w, fmaf(w12, e0w, fmaf(nw11, xj1[k].w, b1))));
        }
    }

    red[tid] = a;
    __syncthreads();
    if (tid < 32) {
        float4 r = red[tid];
        #pragma unroll
        for (int k = 1; k < 8; ++k) {
            float4 o = red[tid + 32 * k];
            r.x += o.x; r.y += o.y; r.z += o.z; r.w += o.w;
        }
        float* ap = aggrP + (size_t)q * 262144 + (size_t)ti * 128 + tid * 4;
        __hip_atomic_store(ap + 0, r.x, __ATOMIC_RELAXED, __HIP_MEMORY_SCOPE_AGENT);
        __hip_atomic_store(ap + 1, r.y, __ATOMIC_RELAXED, __HIP_MEMORY_SCOPE_AGENT);
        __hip_atomic_store(ap + 2, r.z, __ATOMIC_RELAXED, __HIP_MEMORY_SCOPE_AGENT);
        __hip_atomic_store(ap + 3, r.w, __ATOMIC_RELAXED, __HIP_MEMORY_SCOPE_AGENT);
    }
    __syncthreads();
    if (tid == 0)
        sOld = __hip_atomic_fetch_add(&cnt[ti], 1u, __ATOMIC_ACQ_REL, __HIP_MEMORY_SCOPE_AGENT);
    __syncthreads();
    if (sOld != 3u) return;

    // ---- finisher: node update for row ti ----
    int g = tid & 127, half = tid >> 7;
    if (tid < 128) {
        float av = 0.0f;
        #pragma unroll
        for (int qq = 0; qq < 4; ++qq)
            av += __hip_atomic_load(aggrP + (size_t)qq * 262144 + (size_t)ti * 128 + tid,
                                    __ATOMIC_RELAXED, __HIP_MEMORY_SCOPE_AGENT);
        const float* xin = (LAYER == 0) ? x0 : x1;
        float xv = xin[(size_t)t * 16384 + (size_t)i * 128 + tid];
        hs[tid] = lrelu(fmaf(cw[0], xv, cw[1] * av));
    }
    __syncthreads();
    float acc = 0.0f;
    const float* wp = WT + (size_t)(half * 64) * 128 + g;
    #pragma unroll 8
    for (int f = 0; f < 64; ++f) acc = fmaf(hs[half * 64 + f], wp[(size_t)f * 128], acc);
    if (half) ya[g] = acc;
    __syncthreads();
    if (!half) {
        float y = acc + ya[g];
        yb[(size_t)ti * 128 + g] = y;
        int bucket = ti & 31;
        atomicAdd(&bnP[bucket * 256 + g], y);
        atomicAdd(&bnP[bucket * 256 + 128 + g], y * y);
    }
}

// ---------------- D3/D5: BN(scale/shift from buckets) + lrelu + sim (+ x_next writeback) ----------------
// grid (16, 16) x 256.
template<bool WRITE_X>
__global__ __launch_bounds__(256) void simbn_k(const float* __restrict__ yb,
                                               const float* __restrict__ bnP,
                                               const float* __restrict__ gamma,
                                               const float* __restrict__ beta,
                                               float* __restrict__ out,
                                               float* __restrict__ xout) {
    __shared__ float Xs[128][132];
    __shared__ float nrm[128];
    __shared__ float scS[128], shS[128];
    int t = blockIdx.x, ch = blockIdx.y;
    int tid = threadIdx.x;
    int m = tid & 127, rh = tid >> 7;

    if (tid < 128) {
        float s = 0.0f, q = 0.0f;
        #pragma unroll 8
        for (int k = 0; k < 32; ++k) {
            s += bnP[k * 256 + tid];
            q += bnP[k * 256 + 128 + tid];
        }
        const float inv_n = 1.0f / 2048.0f;
        float mu = s * inv_n;
        float var = q * inv_n - mu * mu;
        float sc = rsqrtf(var + 1e-5f) * gamma[tid];
        scS[tid] = sc;
        shS[tid] = beta[tid] - mu * sc;
    }
    __syncthreads();

    const float* xt = yb + (size_t)t * (N_ * F_);
    int fg = (tid & 31) * 4, ko = tid >> 5;
    bool wout = WRITE_X && (ch == 0);
    for (int kb = 0; kb < 128; kb += 8) {
        int k = kb + ko;
        float4 v = *(const float4*)(xt + k * 128 + fg);
        v.x = lrelu(fmaf(v.x, scS[fg], shS[fg]));
        v.y = lrelu(fmaf(v.y, scS[fg + 1], shS[fg + 1]));
        v.z = lrelu(fmaf(v.z, scS[fg + 2], shS[fg + 2]));
        v.w = lrelu(fmaf(v.w, scS[fg + 3], shS[fg + 3]));
        if (wout) *(float4*)(xout + (size_t)t * 16384 + k * 128 + fg) = v;
        *(float4*)&Xs[k][fg] = v;
    }
    __syncthreads();

    if (tid < 128) {
        float s = 0.0f;
        #pragma unroll 8
        for (int f = 0; f < 128; f += 4) {
            float4 v = *(float4*)&Xs[m][f];
            s += v.x * v.x + v.y * v.y + v.z * v.z + v.w * v.w;
        }
        nrm[m] = sqrtf(s);
    }
    __syncthreads();

    float acc[4];
    #pragma unroll
    for (int r = 0; r < 4; ++r) acc[r] = 0.0f;

    for (int fc = 0; fc < 128; fc += 32) {
        float xm[32];
        #pragma unroll
        for (int f = 0; f < 32; f += 4) {
            float4 v = *(float4*)&Xs[m][fc + f];
            xm[f] = v.x; xm[f + 1] = v.y; xm[f + 2] = v.z; xm[f + 3] = v.w;
        }
        #pragma unroll
        for (int r = 0; r < 4; ++r) {
            int n = ch * 8 + rh * 4 + r;
            #pragma unroll
            for (int f = 0; f < 32; f += 4) {
                float4 v = *(float4*)&Xs[n][fc + f];
                acc[r] = fmaf(xm[f], v.x,
                         fmaf(xm[f + 1], v.y,
                         fmaf(xm[f + 2], v.z,
                         fmaf(xm[f + 3], v.w, acc[r]))));
            }
        }
    }

    float nm = nrm[m];
    size_t ob = (size_t)t * 2 * 16384;
    #pragma unroll
    for (int r = 0; r < 4; ++r) {
        int n = ch * 8 + rh * 4 + r;
        float denom = nrm[n] * nm + 1e-6f;
        float sim = __fdividef(acc[r], denom);
        out[ob + (size_t)n * 128 + m] = fminf(fmaxf(sim, 0.0f), 1.0f);
        out[ob + 16384 + (size_t)n * 128 + m] = fminf(fmaxf(1.0f - sim, 0.0f), 1.0f);
    }
}

extern "C" void kernel_launch(void* const* d_in, const int* in_sizes, int n_in,
                              void* d_out, int out_size, void* d_ws, size_t ws_size,
                              hipStream_t stream) {
    const float* x0    = (const float*)d_in[0];
    const float* E     = (const float*)d_in[1];
    const float* ew    = (const float*)d_in[2];
    const float* eb    = (const float*)d_in[3];
    const float* cw    = (const float*)d_in[4];
    const float* nw    = (const float*)d_in[5];
    const float* gamma = (const float*)d_in[6];
    const float* beta  = (const float*)d_in[7];
    float* out = (float*)d_out;

    float* ws    = (float*)d_ws;
    float* x1    = ws;                   // 262144 floats
    float* yb    = ws + 262144;          // 262144 floats
    float* aggrP = ws + 524288;          // 4 x 262144 floats (quarter partials)
    float* bnP   = ws + 1572864;         // 16384 floats (2 layers x 32 buckets x 256)
    float* WT    = ws + 1589248;         // 32768 floats (both layers)
    unsigned int* cnt = (unsigned int*)(ws + 1622016);   // 4096 counters (2 layers x 2048)

    // D1: sim_cal(x0) + W transpose + bnP/cnt zero
    sim0_prep_k<<<dim3(16, 17), 256, 0, stream>>>(x0, nw, WT, bnP, cnt, out);

    // D2: layer-0 edge + last-block node finisher
    edge_nk<0><<<8192, 256, 0, stream>>>(x0, x0, E, ew, eb, cw, WT, aggrP, cnt, yb, bnP);

    // D3: BN + sim, writes x1
    simbn_k<true><<<dim3(16, 16), 256, 0, stream>>>(yb, bnP, gamma, beta, out + 524288, x1);

    // D4: layer-1 edge + finisher (recompute e0 from original E)
    edge_nk<1><<<8192, 256, 0, stream>>>(x0, x1, E, ew, eb, cw + 2, WT + 16384, aggrP,
                                         cnt + 2048, yb, bnP + 8192);

    // D5: BN + sim (no x writeback)
    simbn_k<false><<<dim3(16, 16), 256, 0, stream>>>(yb, bnP + 8192, gamma + 128, beta + 128,
                                                     out + 1048576, nullptr);
}

// Round 8
// 296.984 us; speedup vs baseline: 2.9930x; 2.9930x over previous
//
#include <hip/hip_runtime.h>

#define T_ 16
#define N_ 128
#define F_ 128

__device__ __forceinline__ float fast_tanh(float x) {
    // tanh(x) = 1 - 2/(exp(2x)+1); v_exp_f32 + native rcp-div. Handles +-inf correctly.
    float e = __expf(2.0f * x);
    return 1.0f - __fdividef(2.0f, e + 1.0f);
}

__device__ __forceinline__ float lrelu(float v) {
    return v >= 0.0f ? v : 0.01f * v;
}

// ---------------- D1: role-split merged kernel ----------------
// grid 8464 x 256, 1D. Blocks 0..255: sim_cal(x0) (chunked LDS, t=b>>4, ch=b&15).
// Blocks 256..271: W transpose + bn zero. Blocks 272..8463: layer-0 edge pass (R5-identical).
// All three roles are data-independent. Union LDS = 18.9 KB -> 8 blocks/CU preserved.
union MergedShared {
    float4 red[256];                                   // edge: 4 KB
    struct { float Xs[128][36]; float nrm[128]; } s;   // sim: 18.9 KB ([36] pad: 16B-aligned rows)
};

__global__ __launch_bounds__(256) void merged0_k(const float* __restrict__ x0,
                                                 const float* __restrict__ E,
                                                 const float* __restrict__ ew,
                                                 const float* __restrict__ eb,
                                                 const float* __restrict__ W,
                                                 float* __restrict__ WT,
                                                 float* __restrict__ bn,
                                                 float* __restrict__ aggrP,
                                                 float* __restrict__ out) {
    __shared__ MergedShared sm;
    int b = blockIdx.x;
    int tid = threadIdx.x;

    if (b < 256) {
        // ---- sim_cal(x0) role, 4 x 32-feature chunks ----
        int t = b >> 4, ch = b & 15;
        int m = tid & 127, rh = tid >> 7;
        const float* xt = x0 + (size_t)t * 16384;
        float nacc = 0.0f;
        float acc[4] = {0.f, 0.f, 0.f, 0.f};
        for (int c = 0; c < 4; ++c) {
            #pragma unroll
            for (int qq = 0; qq < 4; ++qq) {
                int q = tid * 4 + qq;            // 0..1023 float4 slots
                int k = q >> 3, f4 = q & 7;
                *(float4*)&sm.s.Xs[k][f4 * 4] =
                    *(const float4*)(xt + k * 128 + c * 32 + f4 * 4);
            }
            __syncthreads();
            if (tid < 128) {
                #pragma unroll
                for (int f = 0; f < 32; f += 4) {
                    float4 v = *(float4*)&sm.s.Xs[m][f];
                    nacc += v.x * v.x + v.y * v.y + v.z * v.z + v.w * v.w;
                }
            }
            #pragma unroll
            for (int f = 0; f < 32; f += 4) {
                float4 vm = *(float4*)&sm.s.Xs[m][f];
                #pragma unroll
                for (int r = 0; r < 4; ++r) {
                    int n = ch * 8 + rh * 4 + r;
                    float4 vn = *(float4*)&sm.s.Xs[n][f];
                    acc[r] = fmaf(vm.x, vn.x,
                             fmaf(vm.y, vn.y,
                             fmaf(vm.z, vn.z,
                             fmaf(vm.w, vn.w, acc[r]))));
                }
            }
            __syncthreads();   // WAR before next chunk load
        }
        if (tid < 128) sm.s.nrm[tid] = sqrtf(nacc);
        __syncthreads();

        float nm = sm.s.nrm[m];
        size_t ob = (size_t)t * 2 * 16384;
        #pragma unroll
        for (int r = 0; r < 4; ++r) {
            int n = ch * 8 + rh * 4 + r;
            float denom = sm.s.nrm[n] * nm + 1e-6f;
            float sim = __fdividef(acc[r], denom);
            out[ob + (size_t)n * 128 + m] = fminf(fmaxf(sim, 0.0f), 1.0f);
            out[ob + 16384 + (size_t)n * 128 + m] = fminf(fmaxf(1.0f - sim, 0.0f), 1.0f);
        }
        return;
    }

    if (b < 272) {
        // ---- prep role: W transpose (32768 elems) + bn zero ----
        int idx4 = (b - 256) * 256 + tid;        // 0..4095
        #pragma unroll
        for (int k = 0; k < 8; ++k) {
            int lin = k * 4096 + idx4;           // 0..32767
            int l = lin >> 14, idx = lin & 16383;
            int g = idx >> 7, f = idx & 127;
            WT[l * 16384 + f * 128 + g] = W[lin];
        }
        if (idx4 < 512) bn[idx4] = 0.0f;         // both layers' BN accumulators
        return;
    }

    // ---- layer-0 edge role (byte-identical math to R5 edge_k<0>) ----
    int bb = b - 272;
    int ti = bb >> 2, q = bb & 3;                // ti = t*128+i, q = j-quarter
    int t = ti >> 7, i = ti & 127;
    int jl = tid >> 5, fg = tid & 31;

    const float4* xt0 = (const float4*)(x0 + (size_t)t * 16384);
    const float4* Ei  = (const float4*)(E + (size_t)ti * 16384);

    float w02 = ew[2], b0 = eb[0];
    float c0 = ew[0] + ew[1], nw01 = -ew[1];

    float4 xi0 = xt0[i * 32 + fg];
    float4 a = make_float4(0.f, 0.f, 0.f, 0.f);
    int jbase = q * 32;

    float4 xj0[4], ev[4];
    #pragma unroll
    for (int k = 0; k < 4; ++k) {
        int j = jbase + k * 8 + jl;
        ev[k]  = Ei[j * 32 + fg];
        xj0[k] = xt0[j * 32 + fg];
    }

    #pragma unroll
    for (int k = 0; k < 4; ++k) {
        int j = jbase + k * 8 + jl;
        float msk = (j != i) ? 1.0f : 0.0f;
        a.x += msk * fast_tanh(fmaf(c0, xi0.x, fmaf(w02, ev[k].x, fmaf(nw01, xj0[k].x, b0))));
        a.y += msk * fast_tanh(fmaf(c0, xi0.y, fmaf(w02, ev[k].y, fmaf(nw01, xj0[k].y, b0))));
        a.z += msk * fast_tanh(fmaf(c0, xi0.z, fmaf(w02, ev[k].z, fmaf(nw01, xj0[k].z, b0))));
        a.w += msk * fast_tanh(fmaf(c0, xi0.w, fmaf(w02, ev[k].w, fmaf(nw01, xj0[k].w, b0))));
    }

    sm.red[tid] = a;
    __syncthreads();
    if (tid < 32) {
        float4 r = sm.red[tid];
        #pragma unroll
        for (int k = 1; k < 8; ++k) {
            float4 o = sm.red[tid + 32 * k];
            r.x += o.x; r.y += o.y; r.z += o.z; r.w += o.w;
        }
        ((float4*)(aggrP + (size_t)q * 262144))[ti * 32 + tid] = r;
    }
}

// ---------------- edge update + partial aggregate, layer 1 (R5-identical) ----------------
// grid 8192 (= (t*128+i)*4 + quarter), block 256 (jl 0..7, fg 0..31).
__global__ __launch_bounds__(256) void edge1_k(const float* __restrict__ x0,
                                               const float* __restrict__ x1,
                                               const float* __restrict__ E,
                                               const float* __restrict__ ew,
                                               const float* __restrict__ eb,
                                               float* __restrict__ aggrP) {
    __shared__ float4 red[256];
    int b = blockIdx.x;
    int ti = b >> 2, q = b & 3;
    int t = ti >> 7, i = ti & 127;
    int tid = threadIdx.x, jl = tid >> 5, fg = tid & 31;

    const float4* xt0 = (const float4*)(x0 + (size_t)t * 16384);
    const float4* xt1 = (const float4*)(x1 + (size_t)t * 16384);
    const float4* Ei  = (const float4*)(E + (size_t)ti * 16384);

    float w02 = ew[2], b0 = eb[0];
    float c0 = ew[0] + ew[1], nw01 = -ew[1];
    float c1 = ew[3] + ew[4], nw11 = -ew[4], w12 = ew[5], b1 = eb[1];

    float4 xi0 = xt0[i * 32 + fg];
    float4 xi1 = xt1[i * 32 + fg];

    float4 a = make_float4(0.f, 0.f, 0.f, 0.f);
    int jbase = q * 32;

    float4 xj0[4], ev[4], xj1[4];
    #pragma unroll
    for (int k = 0; k < 4; ++k) {
        int j = jbase + k * 8 + jl;
        ev[k]  = Ei[j * 32 + fg];
        xj0[k] = xt0[j * 32 + fg];
        xj1[k] = xt1[j * 32 + fg];
    }

    #pragma unroll
    for (int k = 0; k < 4; ++k) {
        int j = jbase + k * 8 + jl;
        float msk = (j != i) ? 1.0f : 0.0f;
        float e0x = fast_tanh(fmaf(c0, xi0.x, fmaf(w02, ev[k].x, fmaf(nw01, xj0[k].x, b0))));
        float e0y = fast_tanh(fmaf(c0, xi0.y, fmaf(w02, ev[k].y, fmaf(nw01, xj0[k].y, b0))));
        float e0z = fast_tanh(fmaf(c0, xi0.z, fmaf(w02, ev[k].z, fmaf(nw01, xj0[k].z, b0))));
        float e0w = fast_tanh(fmaf(c0, xi0.w, fmaf(w02, ev[k].w, fmaf(nw01, xj0[k].w, b0))));
        a.x += msk * fast_tanh(fmaf(c1, xi1.x, fmaf(w12, e0x, fmaf(nw11, xj1[k].x, b1))));
        a.y += msk * fast_tanh(fmaf(c1, xi1.y, fmaf(w12, e0y, fmaf(nw11, xj1[k].y, b1))));
        a.z += msk * fast_tanh(fmaf(c1, xi1.z, fmaf(w12, e0z, fmaf(nw11, xj1[k].z, b1))));
        a.w += msk * fast_tanh(fmaf(c1, xi1.w, fmaf(w12, e0w, fmaf(nw11, xj1[k].w, b1))));
    }

    red[tid] = a;
    __syncthreads();
    if (tid < 32) {
        float4 r = red[tid];
        #pragma unroll
        for (int k = 1; k < 8; ++k) {
            float4 o = red[tid + 32 * k];
            r.x += o.x; r.y += o.y; r.z += o.z; r.w += o.w;
        }
        ((float4*)(aggrP + (size_t)q * 262144))[ti * 32 + tid] = r;
    }
}

// ---------------- node update (R5-identical): h=lrelu(c0*x+c1*sum aggrP); y=h@W^T; BN partials ----
// grid (T, 16), block 128 (thread = g), 8 rows/block.
__global__ __launch_bounds__(128) void node_k(const float* __restrict__ x,
                                              const float* __restrict__ aggrP,
                                              const float* __restrict__ cw,
                                              const float* __restrict__ WT,
                                              float* __restrict__ y_out,
                                              float* __restrict__ bnL) {
    __shared__ float hs[8][128];
    int t = blockIdx.x, ch = blockIdx.y, g = threadIdx.x;
    float c0 = cw[0], c1 = cw[1];
    size_t base = ((size_t)t * 128 + ch * 8) * 128;
    #pragma unroll
    for (int r = 0; r < 8; ++r) {
        float xv = x[base + r * 128 + g];
        float av = aggrP[base + r * 128 + g]
                 + aggrP[262144 + base + r * 128 + g]
                 + aggrP[524288 + base + r * 128 + g]
                 + aggrP[786432 + base + r * 128 + g];
        hs[r][g] = lrelu(fmaf(c0, xv, c1 * av));
    }
    __syncthreads();
    float acc[8];
    #pragma unroll
    for (int r = 0; r < 8; ++r) acc[r] = 0.0f;
    #pragma unroll 4
    for (int f = 0; f < 128; ++f) {
        float wv = WT[f * 128 + g];
        #pragma unroll
        for (int r = 0; r < 8; ++r) acc[r] = fmaf(hs[r][f], wv, acc[r]);
    }
    float s = 0.0f, ss = 0.0f;
    #pragma unroll
    for (int r = 0; r < 8; ++r) {
        y_out[base + r * 128 + g] = acc[r];
        s += acc[r];
        ss += acc[r] * acc[r];
    }
    atomicAdd(&bnL[g], s);
    atomicAdd(&bnL[128 + g], ss);
}

// ---------------- BN-apply + lrelu + sim (+ x_next writeback) (R5-identical) ----------------
// grid (T, 16), block 256 (m = tid&127, row-half = tid>>7).
__global__ __launch_bounds__(256) void simbn_k(const float* __restrict__ yb,
                                               const float* __restrict__ bnS,
                                               const float* __restrict__ gamma,
                                               const float* __restrict__ beta,
                                               float* __restrict__ out,
                                               float* __restrict__ xout) {
    __shared__ float Xs[128][132];
    __shared__ float nrm[128];
    int t = blockIdx.x, ch = blockIdx.y;
    int tid = threadIdx.x;
    int m = tid & 127, rh = tid >> 7;
    const float* xt = yb + (size_t)t * (N_ * F_);
    int fg = (tid & 31) * 4, ko = tid >> 5;

    float4 sc, sh;   // y*sc + sh == (y-mu)*inv*gamma + beta
    {
        float4 s1 = *(const float4*)(bnS + fg);
        float4 s2 = *(const float4*)(bnS + 128 + fg);
        float4 ga = *(const float4*)(gamma + fg);
        float4 be = *(const float4*)(beta + fg);
        const float inv_n = 1.0f / 2048.0f;
        float mx = s1.x * inv_n, my = s1.y * inv_n, mz = s1.z * inv_n, mw = s1.w * inv_n;
        sc.x = rsqrtf(s2.x * inv_n - mx * mx + 1e-5f) * ga.x;
        sc.y = rsqrtf(s2.y * inv_n - my * my + 1e-5f) * ga.y;
        sc.z = rsqrtf(s2.z * inv_n - mz * mz + 1e-5f) * ga.z;
        sc.w = rsqrtf(s2.w * inv_n - mw * mw + 1e-5f) * ga.w;
        sh.x = be.x - mx * sc.x;
        sh.y = be.y - my * sc.y;
        sh.z = be.z - mz * sc.z;
        sh.w = be.w - mw * sc.w;
    }

    bool wout = (blockIdx.y == 0) && (xout != nullptr);
    for (int kb = 0; kb < 128; kb += 8) {
        int k = kb + ko;
        float4 v = *(const float4*)(xt + k * 128 + fg);
        v.x = lrelu(fmaf(v.x, sc.x, sh.x));
        v.y = lrelu(fmaf(v.y, sc.y, sh.y));
        v.z = lrelu(fmaf(v.z, sc.z, sh.z));
        v.w = lrelu(fmaf(v.w, sc.w, sh.w));
        if (wout) *(float4*)(xout + (size_t)t * 16384 + k * 128 + fg) = v;
        *(float4*)&Xs[k][fg] = v;
    }
    __syncthreads();

    if (tid < 128) {
        float s = 0.0f;
        #pragma unroll 8
        for (int f = 0; f < 128; f += 4) {
            float4 v = *(float4*)&Xs[m][f];
            s += v.x * v.x + v.y * v.y + v.z * v.z + v.w * v.w;
        }
        nrm[m] = sqrtf(s);
    }
    __syncthreads();

    float acc[4];
    #pragma unroll
    for (int r = 0; r < 4; ++r) acc[r] = 0.0f;

    for (int fc = 0; fc < 128; fc += 32) {
        float xm[32];
        #pragma unroll
        for (int f = 0; f < 32; f += 4) {
            float4 v = *(float4*)&Xs[m][fc + f];
            xm[f] = v.x; xm[f + 1] = v.y; xm[f + 2] = v.z; xm[f + 3] = v.w;
        }
        #pragma unroll
        for (int r = 0; r < 4; ++r) {
            int n = ch * 8 + rh * 4 + r;
            #pragma unroll
            for (int f = 0; f < 32; f += 4) {
                float4 v = *(float4*)&Xs[n][fc + f];
                acc[r] = fmaf(xm[f], v.x,
                         fmaf(xm[f + 1], v.y,
                         fmaf(xm[f + 2], v.z,
                         fmaf(xm[f + 3], v.w, acc[r]))));
            }
        }
    }

    float nm = nrm[m];
    size_t ob = (size_t)t * 2 * 16384;
    #pragma unroll
    for (int r = 0; r < 4; ++r) {
        int n = ch * 8 + rh * 4 + r;
        float denom = nrm[n] * nm + 1e-6f;
        float sim = __fdividef(acc[r], denom);
        out[ob + (size_t)n * 128 + m] = fminf(fmaxf(sim, 0.0f), 1.0f);
        out[ob + 16384 + (size_t)n * 128 + m] = fminf(fmaxf(1.0f - sim, 0.0f), 1.0f);
    }
}

extern "C" void kernel_launch(void* const* d_in, const int* in_sizes, int n_in,
                              void* d_out, int out_size, void* d_ws, size_t ws_size,
                              hipStream_t stream) {
    const float* x0    = (const float*)d_in[0];
    const float* E     = (const float*)d_in[1];
    const float* ew    = (const float*)d_in[2];
    const float* eb    = (const float*)d_in[3];
    const float* cw    = (const float*)d_in[4];
    const float* nw    = (const float*)d_in[5];
    const float* gamma = (const float*)d_in[6];
    const float* beta  = (const float*)d_in[7];
    float* out = (float*)d_out;

    float* ws    = (float*)d_ws;
    float* x1    = ws;                   // 262144 floats
    float* yb    = ws + 262144;          // 262144 floats
    float* aggrP = ws + 524288;          // 4 x 262144 floats (quarter partials, non-atomic)
    float* bn    = ws + 1572864;         // 512 floats (256 per layer: sum | sumsq)
    float* WT    = ws + 1573376;         // 32768 floats (both layers)

    // D1: sim_cal(x0) + W transpose + bn zero + layer-0 edge pass (role-split)
    merged0_k<<<8464, 256, 0, stream>>>(x0, E, ew, eb, nw, WT, bn, aggrP, out);

    // D2: layer-0 node update
    node_k<<<dim3(16, 16), 128, 0, stream>>>(x0, aggrP, cw, WT, yb, bn);

    // D3: BN + sim, writes x1
    simbn_k<<<dim3(16, 16), 256, 0, stream>>>(yb, bn, gamma, beta, out + 524288, x1);

    // D4: layer-1 edge pass (recompute e0 from original E)
    edge1_k<<<8192, 256, 0, stream>>>(x0, x1, E, ew, eb, aggrP);

    // D5: layer-1 node update
    node_k<<<dim3(16, 16), 128, 0, stream>>>(x1, aggrP, cw + 2, WT + 16384, yb, bn + 256);

    // D6: BN + sim (no x writeback)
    simbn_k<<<dim3(16, 16), 256, 0, stream>>>(yb, bn + 256, gamma + 128, beta + 128,
                                              out + 1048576, nullptr);
}